// Round 14
// baseline (131.909 us; speedup 1.0000x reference)
//
#include <hip/hip_runtime.h>
#include <stdint.h>

typedef unsigned short u16;
typedef short s16x8 __attribute__((ext_vector_type(8)));
typedef float f32x4 __attribute__((ext_vector_type(4)));

#define LOG2E 1.44269504088896340736f

constexpr int Bc = 2, Sc = 4096, Ec = 768, Hc = 12;
constexpr int Mrows = Bc * Sc; // 8192

__device__ __forceinline__ u16 f2b(float x) {
  union { float f; uint32_t u; } v; v.f = x;
  return (u16)((v.u + 0x7FFFu + ((v.u >> 16) & 1u)) >> 16);
}

__device__ __forceinline__ void gld16(const u16* g, u16* l) {
  __builtin_amdgcn_global_load_lds(
      (const __attribute__((address_space(1))) void*)g,
      (__attribute__((address_space(3))) void*)l,
      16, 0, 0);
}

// ---------------- prep: weight transpose-cvts ONLY (hs cvt folded into qkv) ----------------
__global__ __launch_bounds__(256) void k_prep(
    const float* __restrict__ Wq, const float* __restrict__ Wk,
    const float* __restrict__ Wv, const float* __restrict__ Wo,
    u16* __restrict__ wqkvt, u16* __restrict__ wot) {
  __shared__ float tbuf[32][33];
  const int t = blockIdx.x;       // 4 weights x 576 tiles of 32x32
  const int tid = threadIdx.x;
  const int widx = t / 576;
  const int inner = t - widx * 576;
  const float* in = (widx == 0) ? Wq : (widx == 1) ? Wk : (widx == 2) ? Wv : Wo;
  u16* out = (widx < 3) ? (wqkvt + (size_t)widx * Ec * Ec) : wot;
  const int c0 = (inner % 24) * 32, r0 = (inner / 24) * 32;
  const int tx = tid & 31, ty = tid >> 5;
#pragma unroll
  for (int i = 0; i < 32; i += 8)
    tbuf[ty + i][tx] = in[(size_t)(r0 + ty + i) * Ec + c0 + tx];
  __syncthreads();
#pragma unroll
  for (int i = 0; i < 32; i += 8)
    out[(size_t)(c0 + ty + i) * Ec + r0 + tx] = f2b(tbuf[tx][ty + i]);
}

// ======================= QKV GEMM — r12 structure + fused f32 A-conversion (race-fixed) =======================
// 64x128 tile (4 waves of 64x32), BK=32, 2 LDS buffers. A read as f32 from hs:
// float4 loads -> cvt_pk -> ds_write_b128 into the same swizzled bf16 layout.
// RACE FIX vs r13: ALL stores into buffer p^1 (gld16 stageB AND ds_write writeA)
// are issued only AFTER the iter-ki barrier, which guarantees every wave's
// reads of p^1 (iter ki-1) have retired — r12's proven discipline. Bottom:
// vmcnt(0) (loadA regs + stageB landed) -> writeA -> lgkmcnt(0) -> next barrier.
__global__ __launch_bounds__(256) void k_gemm_qkv(
    const float* __restrict__ A, const u16* __restrict__ Bt,
    const float* __restrict__ bq, const float* __restrict__ bk, const float* __restrict__ bv,
    u16* __restrict__ q_ws, u16* __restrict__ k_ws, u16* __restrict__ vt_ws) {
  __shared__ __align__(16) u16 As[2][64 * 32];
  __shared__ __align__(16) u16 Bs[2][128 * 32];
  const int bid = blockIdx.x;
  const int xcd = bid & 7, ii = bid >> 3;          // ii in 0..287
  const int m0 = (xcd * 16 + (ii & 15)) * 64;      // 128 M-tiles, 16 per XCD
  const int n0 = (ii >> 4) * 128;                  // 18 N-tiles
  const int which = n0 / Ec;                       // 0=q 1=k 2=v (uniform)
  const bool isV = (which == 2);
  const int tid = threadIdx.x;
  const int lane = tid & 63, w = tid >> 6;         // wave owns n-cols [w*32, w*32+32)
  const int lr = lane & 15, lg = lane >> 4;

  f32x4 acc[4][2] = {};

  const int row_in = tid >> 2; // 0..63
  const int u = tid & 3;
  // A destination granule (swizzled, bf16): fixed per thread
  const int adst = row_in * 32 + ((u ^ ((row_in >> 1) & 3)) << 3);

  float4 ra0, ra1; // in-flight f32 A elements

  auto loadA = [&](int ki) {
    const float* src = A + (size_t)(m0 + row_in) * Ec + ki * 32 + u * 8;
    ra0 = *reinterpret_cast<const float4*>(src);
    ra1 = *reinterpret_cast<const float4*>(src + 4);
  };
  auto writeA = [&](int p) {
    uint32_t w0, w1, w2, w3;
    asm("v_cvt_pk_bf16_f32 %0, %1, %2" : "=v"(w0) : "v"(ra0.x), "v"(ra0.y));
    asm("v_cvt_pk_bf16_f32 %0, %1, %2" : "=v"(w1) : "v"(ra0.z), "v"(ra0.w));
    asm("v_cvt_pk_bf16_f32 %0, %1, %2" : "=v"(w2) : "v"(ra1.x), "v"(ra1.y));
    asm("v_cvt_pk_bf16_f32 %0, %1, %2" : "=v"(w3) : "v"(ra1.z), "v"(ra1.w));
    uint4 q; q.x = w0; q.y = w1; q.z = w2; q.w = w3;
    *reinterpret_cast<uint4*>(&As[p][adst]) = q;
  };
  auto stageB = [&](int p, int ki) {
    const int k0 = ki * 32;
#pragma unroll
    for (int r2 = 0; r2 < 2; ++r2) {
      const int row = r2 * 64 + row_in;
      const int sc = ((u ^ ((row >> 1) & 3)) << 3);
      gld16(Bt + (size_t)(n0 + row) * Ec + k0 + sc, &Bs[p][(r2 * 64 + w * 16) * 32]);
    }
  };

  constexpr int NK = Ec / 32; // 24
  // prologue: tile 0 fully staged + visible before the first loop barrier
  loadA(0);
  stageB(0, 0);
  asm volatile("s_waitcnt vmcnt(0)" ::: "memory");
  writeA(0);
  asm volatile("s_waitcnt lgkmcnt(0)" ::: "memory");

  for (int ki = 0; ki < NK; ++ki) {
    const int p = ki & 1;
    __builtin_amdgcn_s_barrier(); // buf p staged+visible; all reads of p^1 retired
    if (ki + 1 < NK) { loadA(ki + 1); stageB(p ^ 1, ki + 1); } // post-barrier: safe
    s16x8 af[4], bf[2];
#pragma unroll
    for (int i = 0; i < 4; ++i) {
      const int ra = i * 16 + lr;
      af[i] = *reinterpret_cast<const s16x8*>(&As[p][ra * 32 + ((lg ^ ((ra >> 1) & 3)) << 3)]);
    }
#pragma unroll
    for (int i = 0; i < 2; ++i) {
      const int rb = w * 32 + i * 16 + lr;
      bf[i] = *reinterpret_cast<const s16x8*>(&Bs[p][rb * 32 + ((lg ^ ((rb >> 1) & 3)) << 3)]);
    }
    __builtin_amdgcn_s_setprio(1);
    if (isV) {
#pragma unroll
      for (int mf = 0; mf < 4; ++mf)
#pragma unroll
        for (int nf = 0; nf < 2; ++nf)
          acc[mf][nf] = __builtin_amdgcn_mfma_f32_16x16x32_bf16(af[mf], bf[nf], acc[mf][nf], 0, 0, 0);
    } else {
#pragma unroll
      for (int nf = 0; nf < 2; ++nf)
#pragma unroll
        for (int mf = 0; mf < 4; ++mf)
          acc[mf][nf] = __builtin_amdgcn_mfma_f32_16x16x32_bf16(bf[nf], af[mf], acc[mf][nf], 0, 0, 0);
    }
    __builtin_amdgcn_s_setprio(0);
    if (ki + 1 < NK) {
      asm volatile("s_waitcnt vmcnt(0)" ::: "memory"); // loadA regs + stageB gld16 landed
      writeA(p ^ 1);                                   // post-barrier(ki): p^1 reads retired
      asm volatile("s_waitcnt lgkmcnt(0)" ::: "memory"); // visible before next barrier
    }
  }

  if (isV) {
#pragma unroll
    for (int nf = 0; nf < 2; ++nf) {
      const int nl = (n0 - 2 * Ec) + w * 32 + nf * 16 + lr;
      const int hh = nl >> 6, dd = nl & 63;
      const float bias = bv[nl];
#pragma unroll
      for (int mf = 0; mf < 4; ++mf) {
        const int mg = m0 + mf * 16 + lg * 4;
        const int bb = mg >> 12, ss = mg & (Sc - 1);
        const int bh = bb * Hc + hh;
        ushort4 pk;
        pk.x = f2b(acc[mf][nf][0] + bias);
        pk.y = f2b(acc[mf][nf][1] + bias);
        pk.z = f2b(acc[mf][nf][2] + bias);
        pk.w = f2b(acc[mf][nf][3] + bias);
        *reinterpret_cast<ushort4*>(&vt_ws[((size_t)bh * 64 + dd) * Sc + ss]) = pk;
      }
    }
  } else {
    const float* bptr = (which == 0) ? bq : bk;
    u16* dst = (which == 0) ? q_ws : k_ws;
    const float scl = (which == 0) ? 0.125f : 1.0f;
    const int nbase = n0 - which * Ec;
#pragma unroll
    for (int nf = 0; nf < 2; ++nf) {
      const int nl0 = nbase + w * 32 + nf * 16 + lg * 4;
      const int hh = nl0 >> 6, dd0 = nl0 & 63;
      const float4 b4 = *reinterpret_cast<const float4*>(bptr + nl0);
#pragma unroll
      for (int mf = 0; mf < 4; ++mf) {
        const int tok = m0 + mf * 16 + lr;
        const int bb = tok >> 12, ss = tok & (Sc - 1);
        const float v0 = (acc[mf][nf][0] + b4.x) * scl;
        const float v1 = (acc[mf][nf][1] + b4.y) * scl;
        const float v2 = (acc[mf][nf][2] + b4.z) * scl;
        const float v3 = (acc[mf][nf][3] + b4.w) * scl;
        uint32_t w0, w1;
        asm("v_cvt_pk_bf16_f32 %0, %1, %2" : "=v"(w0) : "v"(v0), "v"(v1));
        asm("v_cvt_pk_bf16_f32 %0, %1, %2" : "=v"(w1) : "v"(v2), "v"(v3));
        uint2 d; d.x = w0; d.y = w1;
        *reinterpret_cast<uint2*>(&dst[((size_t)((bb * Hc + hh) * Sc + ss)) * 64 + dd0]) = d;
      }
    }
  }
}

// ======================= output GEMM (r12 structure, unchanged) =======================
__global__ __launch_bounds__(256) void k_gemm_out(
    const u16* __restrict__ A, const u16* __restrict__ Bt,
    const float* __restrict__ bo, float* __restrict__ out) {
  __shared__ __align__(16) u16 As[2][64 * 32];
  __shared__ __align__(16) u16 Bs[2][128 * 32];
  const int bid = blockIdx.x;
  const int xcd = bid & 7, ii = bid >> 3;          // ii in 0..95
  const int m0 = (xcd * 16 + (ii & 15)) * 64;
  const int n0 = (ii >> 4) * 128;                  // 6 N-tiles
  const int tid = threadIdx.x;
  const int lane = tid & 63, w = tid >> 6;
  const int lr = lane & 15, lg = lane >> 4;

  f32x4 acc[4][2] = {};
  const int row_in = tid >> 2;
  const int u = tid & 3;

  auto stage = [&](int p, int ki) {
    const int k0 = ki * 32;
    {
      const int sc = ((u ^ ((row_in >> 1) & 3)) << 3);
      gld16(A + (size_t)(m0 + row_in) * Ec + k0 + sc, &As[p][(w * 16) * 32]);
    }
#pragma unroll
    for (int r2 = 0; r2 < 2; ++r2) {
      const int row = r2 * 64 + row_in;
      const int sc = ((u ^ ((row >> 1) & 3)) << 3);
      gld16(Bt + (size_t)(n0 + row) * Ec + k0 + sc, &Bs[p][(r2 * 64 + w * 16) * 32]);
    }
  };

  constexpr int NK = Ec / 32; // 24
  stage(0, 0);
  for (int ki = 0; ki < NK; ++ki) {
    const int p = ki & 1;
    asm volatile("s_waitcnt vmcnt(0)" ::: "memory");
    __builtin_amdgcn_s_barrier();
    if (ki + 1 < NK) stage(p ^ 1, ki + 1);
    s16x8 af[4], bf[2];
#pragma unroll
    for (int i = 0; i < 4; ++i) {
      const int ra = i * 16 + lr;
      af[i] = *reinterpret_cast<const s16x8*>(&As[p][ra * 32 + ((lg ^ ((ra >> 1) & 3)) << 3)]);
    }
#pragma unroll
    for (int i = 0; i < 2; ++i) {
      const int rb = w * 32 + i * 16 + lr;
      bf[i] = *reinterpret_cast<const s16x8*>(&Bs[p][rb * 32 + ((lg ^ ((rb >> 1) & 3)) << 3)]);
    }
    __builtin_amdgcn_s_setprio(1);
#pragma unroll
    for (int nf = 0; nf < 2; ++nf)
#pragma unroll
      for (int mf = 0; mf < 4; ++mf)
        acc[mf][nf] = __builtin_amdgcn_mfma_f32_16x16x32_bf16(bf[nf], af[mf], acc[mf][nf], 0, 0, 0);
    __builtin_amdgcn_s_setprio(0);
  }

#pragma unroll
  for (int nf = 0; nf < 2; ++nf) {
    const int f0 = n0 + w * 32 + nf * 16 + lg * 4;
    const float4 b4 = *reinterpret_cast<const float4*>(bo + f0);
#pragma unroll
    for (int mf = 0; mf < 4; ++mf) {
      const int tok = m0 + mf * 16 + lr;
      float4 o;
      o.x = acc[mf][nf][0] + b4.x;
      o.y = acc[mf][nf][1] + b4.y;
      o.z = acc[mf][nf][2] + b4.z;
      o.w = acc[mf][nf][3] + b4.w;
      *reinterpret_cast<float4*>(&out[(size_t)tok * Ec + f0]) = o;
    }
  }
}

// ---------------- local attention: 2 chunks per block (round-9, verified) ----------------
__global__ __launch_bounds__(512) void k_attn(
    const u16* __restrict__ q_ws, const u16* __restrict__ k_ws,
    const u16* __restrict__ vt_ws, u16* __restrict__ ctx_ws) {
  __shared__ __align__(16) u16 Kb[2][64 * 64];
  __shared__ __align__(16) u16 Vb[2][64 * 64];
  __shared__ __align__(16) u16 P[8][16 * 72];
  const int lin = blockIdx.x;
  const int work = (lin & 7) * 96 + (lin >> 3);
  const int bh = work >> 5;
  const int cp = work & 31;
  const int c0 = cp * 2;
  const int tid = threadIdx.x;
  const int lane = tid & 63, w = tid >> 6;
  const int dc = w >> 2;
  const int cw = c0 + dc;
  const int b = bh / Hc, h = bh - b * Hc;
  const int lr = lane & 15, lg = lane >> 4;

  const u16* qb = q_ws + (size_t)bh * Sc * 64;
  const u16* kb = k_ws + (size_t)bh * Sc * 64;
  const u16* vb = vt_ws + (size_t)bh * 64 * Sc;

  const int qrow = cw * 64 + (w & 3) * 16 + lr;
  const s16x8 qf0 = *reinterpret_cast<const s16x8*>(&qb[(size_t)qrow * 64 + lg * 8]);
  const s16x8 qf1 = *reinterpret_cast<const s16x8*>(&qb[(size_t)qrow * 64 + 32 + lg * 8]);

  float mrow = -3e38f;
  float ssum = 0.f;
  f32x4 ctx[4] = {};

  const int su0 = (c0 < 4) ? 4 - c0 : 0;
  const int su1 = (68 - c0 < 10) ? 68 - c0 : 10;
  u16* pw = &P[w][0];

  const int srow = tid >> 3;
  const int su8 = tid & 7;

  auto stage = [&](int p, int ut) {
    const int key0 = (c0 - 4 + ut) * 64;
    const int sw = ((su8 ^ (srow & 7)) << 3);
    gld16(kb + (size_t)(key0 + srow) * 64 + sw, &Kb[p][w * 512]);
    gld16(vb + (size_t)srow * Sc + key0 + sw, &Vb[p][w * 512]);
  };

  auto compute = [&](int p) {
    const u16* kt = &Kb[p][0];
    const u16* vt = &Vb[p][0];
    s16x8 kf[4][2];
#pragma unroll
    for (int nt = 0; nt < 4; ++nt) {
      const int row = nt * 16 + lr;
      const int x = row & 7;
#pragma unroll
      for (int ks = 0; ks < 2; ++ks) {
        const int c = ((ks * 4 + lg) ^ x) << 3;
        kf[nt][ks] = *reinterpret_cast<const s16x8*>(&kt[row * 64 + c]);
      }
    }
    f32x4 sv[4];
    __builtin_amdgcn_s_setprio(1);
#pragma unroll
    for (int nt = 0; nt < 4; ++nt) {
      f32x4 z = {};
      z = __builtin_amdgcn_mfma_f32_16x16x32_bf16(kf[nt][0], qf0, z, 0, 0, 0);
      z = __builtin_amdgcn_mfma_f32_16x16x32_bf16(kf[nt][1], qf1, z, 0, 0, 0);
      sv[nt] = z;
    }
    __builtin_amdgcn_s_setprio(0);
    s16x8 vf[4][2];
#pragma unroll
    for (int nt = 0; nt < 4; ++nt) {
      const int row = nt * 16 + lr;
      const int x = row & 7;
#pragma unroll
      for (int ks = 0; ks < 2; ++ks) {
        const int c = ((ks * 4 + lg) ^ x) << 3;
        vf[nt][ks] = *reinterpret_cast<const s16x8*>(&vt[row * 64 + c]);
      }
    }
    float pm;
    {
      f32x4 m4 = sv[0];
      m4 = {fmaxf(m4[0], sv[1][0]), fmaxf(m4[1], sv[1][1]), fmaxf(m4[2], sv[1][2]), fmaxf(m4[3], sv[1][3])};
      m4 = {fmaxf(m4[0], sv[2][0]), fmaxf(m4[1], sv[2][1]), fmaxf(m4[2], sv[2][2]), fmaxf(m4[3], sv[2][3])};
      m4 = {fmaxf(m4[0], sv[3][0]), fmaxf(m4[1], sv[3][1]), fmaxf(m4[2], sv[3][2]), fmaxf(m4[3], sv[3][3])};
      pm = fmaxf(fmaxf(m4[0], m4[1]), fmaxf(m4[2], m4[3]));
    }
    pm = fmaxf(pm, __shfl_xor(pm, 16));
    pm = fmaxf(pm, __shfl_xor(pm, 32));
    if (!__all(pm <= mrow + 5.0f)) {
      const float mn = fmaxf(mrow, pm);
      const float scl = exp2f((mrow - mn) * LOG2E);
      ssum *= scl;
      float sc[4];
#pragma unroll
      for (int r = 0; r < 4; ++r) sc[r] = __shfl(scl, (lg << 2) | r);
#pragma unroll
      for (int nt = 0; nt < 4; ++nt)
#pragma unroll
        for (int r = 0; r < 4; ++r) ctx[nt][r] *= sc[r];
      mrow = mn;
    }
    const float ml2e = mrow * LOG2E;
    float ps = 0.f;
    uint32_t pk[4][2];
#pragma unroll
    for (int nt = 0; nt < 4; ++nt) {
      const float p0 = exp2f(sv[nt][0] * LOG2E - ml2e);
      const float p1 = exp2f(sv[nt][1] * LOG2E - ml2e);
      const float p2 = exp2f(sv[nt][2] * LOG2E - ml2e);
      const float p3 = exp2f(sv[nt][3] * LOG2E - ml2e);
      ps += (p0 + p1) + (p2 + p3);
      asm("v_cvt_pk_bf16_f32 %0, %1, %2" : "=v"(pk[nt][0]) : "v"(p0), "v"(p1));
      asm("v_cvt_pk_bf16_f32 %0, %1, %2" : "=v"(pk[nt][1]) : "v"(p2), "v"(p3));
    }
    ssum += ps;
#pragma unroll
    for (int nt = 0; nt < 4; ++nt) {
      uint2 d; d.x = pk[nt][0]; d.y = pk[nt][1];
      *reinterpret_cast<uint2*>(&pw[lr * 72 + nt * 16 + lg * 4]) = d;
    }
    asm volatile("s_waitcnt lgkmcnt(0)" ::: "memory");
    __builtin_amdgcn_sched_barrier(0);
    const s16x8 pa0 = *reinterpret_cast<const s16x8*>(&pw[lr * 72 + lg * 8]);
    const s16x8 pa1 = *reinterpret_cast<const s16x8*>(&pw[lr * 72 + 32 + lg * 8]);
    __builtin_amdgcn_s_setprio(1);
#pragma unroll
    for (int nt = 0; nt < 4; ++nt) {
      ctx[nt] = __builtin_amdgcn_mfma_f32_16x16x32_bf16(pa0, vf[nt][0], ctx[nt], 0, 0, 0);
      ctx[nt] = __builtin_amdgcn_mfma_f32_16x16x32_bf16(pa1, vf[nt][1], ctx[nt], 0, 0, 0);
    }
    __builtin_amdgcn_s_setprio(0);
  };

  int p = 0;
  stage(0, su0);
  for (int ut = su0; ut < su1; ++ut) {
    __builtin_amdgcn_s_barrier();
    if (ut + 1 < su1) {
      stage(p ^ 1, ut + 1);
      asm volatile("s_waitcnt vmcnt(2)" ::: "memory");
    } else {
      asm volatile("s_waitcnt vmcnt(0)" ::: "memory");
    }
    __builtin_amdgcn_s_barrier();
    if (ut >= dc && ut <= 8 + dc) compute(p);
    p ^= 1;
  }

  float s = ssum;
  s += __shfl_xor(s, 16);
  s += __shfl_xor(s, 32);
  const float invq = 1.f / s;
  float ic[4];
#pragma unroll
  for (int r = 0; r < 4; ++r) ic[r] = __shfl(invq, (lg << 2) | r);

  const int tok = cw * 64 + (w & 3) * 16 + lg * 4;
#pragma unroll
  for (int nt = 0; nt < 4; ++nt) {
    const int col = h * 64 + nt * 16 + lr;
#pragma unroll
    for (int r = 0; r < 4; ++r)
      ctx_ws[(size_t)(b * Sc + tok + r) * Ec + col] = f2b(ctx[nt][r] * ic[r]);
  }
}

extern "C" void kernel_launch(void* const* d_in, const int* in_sizes, int n_in,
                              void* d_out, int out_size, void* d_ws, size_t ws_size,
                              hipStream_t stream) {
  const float* hs = (const float*)d_in[0];
  const float* Wq = (const float*)d_in[1];
  const float* bq = (const float*)d_in[2];
  const float* Wk = (const float*)d_in[3];
  const float* bk = (const float*)d_in[4];
  const float* Wv = (const float*)d_in[5];
  const float* bv = (const float*)d_in[6];
  const float* Wo = (const float*)d_in[7];
  const float* bo = (const float*)d_in[8];
  float* out = (float*)d_out;

  char* ws = (char*)d_ws;
  size_t o = 0;
  u16* wqkvt = (u16*)(ws + o); o += (size_t)3 * Ec * Ec * 2;
  u16* wot = (u16*)(ws + o);   o += (size_t)Ec * Ec * 2;
  u16* q_ws = (u16*)(ws + o);  o += (size_t)Mrows * Ec * 2;      // [b,h,s,d]
  u16* k_ws = (u16*)(ws + o);  o += (size_t)Mrows * Ec * 2;      // [b,h,s,d]
  u16* vt_ws = (u16*)(ws + o); o += (size_t)Mrows * Ec * 2;      // [b,h,d,s]
  u16* ctx_ws = (u16*)(ws + o); o += (size_t)Mrows * Ec * 2;     // [b*s, e]

  k_prep<<<4 * 576, 256, 0, stream>>>(Wq, Wk, Wv, Wo, wqkvt, wot);

  k_gemm_qkv<<<2304, 256, 0, stream>>>(hs, wqkvt, bq, bk, bv, q_ws, k_ws, vt_ws);

  k_attn<<<768, 512, 0, stream>>>(q_ws, k_ws, vt_ws, ctx_ws);

  k_gemm_out<<<768, 256, 0, stream>>>(ctx_ws, wot, bo, out);
}

// Round 15
// 126.885 us; speedup vs baseline: 1.0396x; 1.0396x over previous
//
#include <hip/hip_runtime.h>
#include <stdint.h>

typedef unsigned short u16;
typedef short s16x8 __attribute__((ext_vector_type(8)));
typedef float f32x4 __attribute__((ext_vector_type(4)));

#define LOG2E 1.44269504088896340736f

constexpr int Bc = 2, Sc = 4096, Ec = 768, Hc = 12;
constexpr int Mrows = Bc * Sc; // 8192

__device__ __forceinline__ u16 f2b(float x) {
  union { float f; uint32_t u; } v; v.f = x;
  return (u16)((v.u + 0x7FFFu + ((v.u >> 16) & 1u)) >> 16);
}

__device__ __forceinline__ void gld16(const u16* g, u16* l) {
  __builtin_amdgcn_global_load_lds(
      (const __attribute__((address_space(1))) void*)g,
      (__attribute__((address_space(3))) void*)l,
      16, 0, 0);
}

// ---------------- fused prep: hs cvt + 4 weight transpose-cvts ----------------
__global__ __launch_bounds__(256) void k_prep(
    const float* __restrict__ hs, u16* __restrict__ hsb, int nhs,
    const float* __restrict__ Wq, const float* __restrict__ Wk,
    const float* __restrict__ Wv, const float* __restrict__ Wo,
    u16* __restrict__ wqkvt, u16* __restrict__ wot) {
  __shared__ float tbuf[32][33];
  const int bid = blockIdx.x;
  const int tid = threadIdx.x;
  if (bid < 6144) { // cvt: 6144 * 1024 elems = nhs
    const int i = (bid * 256 + tid) * 4;
    if (i >= nhs) return;
    const float4 v = *reinterpret_cast<const float4*>(hs + i);
    ushort4 o;
    o.x = f2b(v.x); o.y = f2b(v.y); o.z = f2b(v.z); o.w = f2b(v.w);
    *reinterpret_cast<ushort4*>(hsb + i) = o;
  } else { // transpose-cvt: 4 weights x 576 tiles of 32x32
    const int t = bid - 6144;
    const int widx = t / 576;
    const int inner = t - widx * 576;
    const float* in = (widx == 0) ? Wq : (widx == 1) ? Wk : (widx == 2) ? Wv : Wo;
    u16* out = (widx < 3) ? (wqkvt + (size_t)widx * Ec * Ec) : wot;
    const int c0 = (inner % 24) * 32, r0 = (inner / 24) * 32;
    const int tx = tid & 31, ty = tid >> 5;
#pragma unroll
    for (int i = 0; i < 32; i += 8)
      tbuf[ty + i][tx] = in[(size_t)(r0 + ty + i) * Ec + c0 + tx];
    __syncthreads();
#pragma unroll
    for (int i = 0; i < 32; i += 8)
      out[(size_t)(c0 + ty + i) * Ec + r0 + tx] = f2b(tbuf[tx][ty + i]);
  }
}

// ======================= QKV GEMM — r12 (best measured: 62.5 µs) =======================
// 64x128 tile (4 waves of 64x32), BK=32, TWO LDS buffers (24 KB), stage(k+1)
// issued post-barrier, vmcnt(0) at iter top. Eight schedule families measured
// 62.5-79 µs for this latency-floored M=8192/K=768 shape; this is the floor.
// Conflicts 0; WRITE ideal.
__global__ __launch_bounds__(256) void k_gemm_qkv(
    const u16* __restrict__ A, const u16* __restrict__ Bt,
    const float* __restrict__ bq, const float* __restrict__ bk, const float* __restrict__ bv,
    u16* __restrict__ q_ws, u16* __restrict__ k_ws, u16* __restrict__ vt_ws) {
  __shared__ __align__(16) u16 As[2][64 * 32];
  __shared__ __align__(16) u16 Bs[2][128 * 32];
  const int bid = blockIdx.x;
  const int xcd = bid & 7, ii = bid >> 3;          // ii in 0..287
  const int m0 = (xcd * 16 + (ii & 15)) * 64;      // 128 M-tiles, 16 per XCD
  const int n0 = (ii >> 4) * 128;                  // 18 N-tiles
  const int which = n0 / Ec;                       // 0=q 1=k 2=v (uniform)
  const bool isV = (which == 2);
  const int tid = threadIdx.x;
  const int lane = tid & 63, w = tid >> 6;         // wave owns n-cols [w*32, w*32+32)
  const int lr = lane & 15, lg = lane >> 4;

  f32x4 acc[4][2] = {};

  const int row_in = tid >> 2; // 0..63
  const int u = tid & 3;

  auto stage = [&](int p, int ki) {
    const int k0 = ki * 32;
    {
      const int sc = ((u ^ ((row_in >> 1) & 3)) << 3);
      gld16(A + (size_t)(m0 + row_in) * Ec + k0 + sc, &As[p][(w * 16) * 32]);
    }
#pragma unroll
    for (int r2 = 0; r2 < 2; ++r2) {
      const int row = r2 * 64 + row_in;
      const int sc = ((u ^ ((row >> 1) & 3)) << 3);
      gld16(Bt + (size_t)(n0 + row) * Ec + k0 + sc, &Bs[p][(r2 * 64 + w * 16) * 32]);
    }
  };

  constexpr int NK = Ec / 32; // 24
  stage(0, 0);
  for (int ki = 0; ki < NK; ++ki) {
    const int p = ki & 1;
    asm volatile("s_waitcnt vmcnt(0)" ::: "memory"); // buf[p] staged (1-iter cover)
    __builtin_amdgcn_s_barrier();
    if (ki + 1 < NK) stage(p ^ 1, ki + 1);           // hides under compute below
    s16x8 af[4], bf[2];
#pragma unroll
    for (int i = 0; i < 4; ++i) {
      const int ra = i * 16 + lr;
      af[i] = *reinterpret_cast<const s16x8*>(&As[p][ra * 32 + ((lg ^ ((ra >> 1) & 3)) << 3)]);
    }
#pragma unroll
    for (int i = 0; i < 2; ++i) {
      const int rb = w * 32 + i * 16 + lr;
      bf[i] = *reinterpret_cast<const s16x8*>(&Bs[p][rb * 32 + ((lg ^ ((rb >> 1) & 3)) << 3)]);
    }
    __builtin_amdgcn_s_setprio(1);
    if (isV) {
#pragma unroll
      for (int mf = 0; mf < 4; ++mf)
#pragma unroll
        for (int nf = 0; nf < 2; ++nf)
          acc[mf][nf] = __builtin_amdgcn_mfma_f32_16x16x32_bf16(af[mf], bf[nf], acc[mf][nf], 0, 0, 0);
    } else {
#pragma unroll
      for (int nf = 0; nf < 2; ++nf)
#pragma unroll
        for (int mf = 0; mf < 4; ++mf)
          acc[mf][nf] = __builtin_amdgcn_mfma_f32_16x16x32_bf16(bf[nf], af[mf], acc[mf][nf], 0, 0, 0);
    }
    __builtin_amdgcn_s_setprio(0);
  }

  if (isV) {
#pragma unroll
    for (int nf = 0; nf < 2; ++nf) {
      const int nl = (n0 - 2 * Ec) + w * 32 + nf * 16 + lr;
      const int hh = nl >> 6, dd = nl & 63;
      const float bias = bv[nl];
#pragma unroll
      for (int mf = 0; mf < 4; ++mf) {
        const int mg = m0 + mf * 16 + lg * 4;
        const int bb = mg >> 12, ss = mg & (Sc - 1);
        const int bh = bb * Hc + hh;
        ushort4 pk;
        pk.x = f2b(acc[mf][nf][0] + bias);
        pk.y = f2b(acc[mf][nf][1] + bias);
        pk.z = f2b(acc[mf][nf][2] + bias);
        pk.w = f2b(acc[mf][nf][3] + bias);
        *reinterpret_cast<ushort4*>(&vt_ws[((size_t)bh * 64 + dd) * Sc + ss]) = pk;
      }
    }
  } else {
    const float* bptr = (which == 0) ? bq : bk;
    u16* dst = (which == 0) ? q_ws : k_ws;
    const float scl = (which == 0) ? 0.125f : 1.0f;
    const int nbase = n0 - which * Ec;
#pragma unroll
    for (int nf = 0; nf < 2; ++nf) {
      const int nl0 = nbase + w * 32 + nf * 16 + lg * 4;
      const int hh = nl0 >> 6, dd0 = nl0 & 63;
      const float4 b4 = *reinterpret_cast<const float4*>(bptr + nl0);
#pragma unroll
      for (int mf = 0; mf < 4; ++mf) {
        const int tok = m0 + mf * 16 + lr;
        const int bb = tok >> 12, ss = tok & (Sc - 1);
        const float v0 = (acc[mf][nf][0] + b4.x) * scl;
        const float v1 = (acc[mf][nf][1] + b4.y) * scl;
        const float v2 = (acc[mf][nf][2] + b4.z) * scl;
        const float v3 = (acc[mf][nf][3] + b4.w) * scl;
        uint32_t w0, w1;
        asm("v_cvt_pk_bf16_f32 %0, %1, %2" : "=v"(w0) : "v"(v0), "v"(v1));
        asm("v_cvt_pk_bf16_f32 %0, %1, %2" : "=v"(w1) : "v"(v2), "v"(v3));
        uint2 d; d.x = w0; d.y = w1;
        *reinterpret_cast<uint2*>(&dst[((size_t)((bb * Hc + hh) * Sc + ss)) * 64 + dd0]) = d;
      }
    }
  }
}

// ======================= output GEMM — same 2-buffer structure =======================
__global__ __launch_bounds__(256) void k_gemm_out(
    const u16* __restrict__ A, const u16* __restrict__ Bt,
    const float* __restrict__ bo, float* __restrict__ out) {
  __shared__ __align__(16) u16 As[2][64 * 32];
  __shared__ __align__(16) u16 Bs[2][128 * 32];
  const int bid = blockIdx.x;
  const int xcd = bid & 7, ii = bid >> 3;          // ii in 0..95
  const int m0 = (xcd * 16 + (ii & 15)) * 64;
  const int n0 = (ii >> 4) * 128;                  // 6 N-tiles
  const int tid = threadIdx.x;
  const int lane = tid & 63, w = tid >> 6;
  const int lr = lane & 15, lg = lane >> 4;

  f32x4 acc[4][2] = {};
  const int row_in = tid >> 2;
  const int u = tid & 3;

  auto stage = [&](int p, int ki) {
    const int k0 = ki * 32;
    {
      const int sc = ((u ^ ((row_in >> 1) & 3)) << 3);
      gld16(A + (size_t)(m0 + row_in) * Ec + k0 + sc, &As[p][(w * 16) * 32]);
    }
#pragma unroll
    for (int r2 = 0; r2 < 2; ++r2) {
      const int row = r2 * 64 + row_in;
      const int sc = ((u ^ ((row >> 1) & 3)) << 3);
      gld16(Bt + (size_t)(n0 + row) * Ec + k0 + sc, &Bs[p][(r2 * 64 + w * 16) * 32]);
    }
  };

  constexpr int NK = Ec / 32; // 24
  stage(0, 0);
  for (int ki = 0; ki < NK; ++ki) {
    const int p = ki & 1;
    asm volatile("s_waitcnt vmcnt(0)" ::: "memory");
    __builtin_amdgcn_s_barrier();
    if (ki + 1 < NK) stage(p ^ 1, ki + 1);
    s16x8 af[4], bf[2];
#pragma unroll
    for (int i = 0; i < 4; ++i) {
      const int ra = i * 16 + lr;
      af[i] = *reinterpret_cast<const s16x8*>(&As[p][ra * 32 + ((lg ^ ((ra >> 1) & 3)) << 3)]);
    }
#pragma unroll
    for (int i = 0; i < 2; ++i) {
      const int rb = w * 32 + i * 16 + lr;
      bf[i] = *reinterpret_cast<const s16x8*>(&Bs[p][rb * 32 + ((lg ^ ((rb >> 1) & 3)) << 3)]);
    }
    __builtin_amdgcn_s_setprio(1);
#pragma unroll
    for (int nf = 0; nf < 2; ++nf)
#pragma unroll
      for (int mf = 0; mf < 4; ++mf)
        acc[mf][nf] = __builtin_amdgcn_mfma_f32_16x16x32_bf16(bf[nf], af[mf], acc[mf][nf], 0, 0, 0);
    __builtin_amdgcn_s_setprio(0);
  }

#pragma unroll
  for (int nf = 0; nf < 2; ++nf) {
    const int f0 = n0 + w * 32 + nf * 16 + lg * 4;
    const float4 b4 = *reinterpret_cast<const float4*>(bo + f0);
#pragma unroll
    for (int mf = 0; mf < 4; ++mf) {
      const int tok = m0 + mf * 16 + lr;
      float4 o;
      o.x = acc[mf][nf][0] + b4.x;
      o.y = acc[mf][nf][1] + b4.y;
      o.z = acc[mf][nf][2] + b4.z;
      o.w = acc[mf][nf][3] + b4.w;
      *reinterpret_cast<float4*>(&out[(size_t)tok * Ec + f0]) = o;
    }
  }
}

// ---------------- local attention: 2 chunks per block (round-9, verified) ----------------
__global__ __launch_bounds__(512) void k_attn(
    const u16* __restrict__ q_ws, const u16* __restrict__ k_ws,
    const u16* __restrict__ vt_ws, u16* __restrict__ ctx_ws) {
  __shared__ __align__(16) u16 Kb[2][64 * 64];
  __shared__ __align__(16) u16 Vb[2][64 * 64];
  __shared__ __align__(16) u16 P[8][16 * 72];
  const int lin = blockIdx.x;
  const int work = (lin & 7) * 96 + (lin >> 3);
  const int bh = work >> 5;
  const int cp = work & 31;
  const int c0 = cp * 2;
  const int tid = threadIdx.x;
  const int lane = tid & 63, w = tid >> 6;
  const int dc = w >> 2;
  const int cw = c0 + dc;
  const int b = bh / Hc, h = bh - b * Hc;
  const int lr = lane & 15, lg = lane >> 4;

  const u16* qb = q_ws + (size_t)bh * Sc * 64;
  const u16* kb = k_ws + (size_t)bh * Sc * 64;
  const u16* vb = vt_ws + (size_t)bh * 64 * Sc;

  const int qrow = cw * 64 + (w & 3) * 16 + lr;
  const s16x8 qf0 = *reinterpret_cast<const s16x8*>(&qb[(size_t)qrow * 64 + lg * 8]);
  const s16x8 qf1 = *reinterpret_cast<const s16x8*>(&qb[(size_t)qrow * 64 + 32 + lg * 8]);

  float mrow = -3e38f;
  float ssum = 0.f;
  f32x4 ctx[4] = {};

  const int su0 = (c0 < 4) ? 4 - c0 : 0;
  const int su1 = (68 - c0 < 10) ? 68 - c0 : 10;
  u16* pw = &P[w][0];

  const int srow = tid >> 3;
  const int su8 = tid & 7;

  auto stage = [&](int p, int ut) {
    const int key0 = (c0 - 4 + ut) * 64;
    const int sw = ((su8 ^ (srow & 7)) << 3);
    gld16(kb + (size_t)(key0 + srow) * 64 + sw, &Kb[p][w * 512]);
    gld16(vb + (size_t)srow * Sc + key0 + sw, &Vb[p][w * 512]);
  };

  auto compute = [&](int p) {
    const u16* kt = &Kb[p][0];
    const u16* vt = &Vb[p][0];
    s16x8 kf[4][2];
#pragma unroll
    for (int nt = 0; nt < 4; ++nt) {
      const int row = nt * 16 + lr;
      const int x = row & 7;
#pragma unroll
      for (int ks = 0; ks < 2; ++ks) {
        const int c = ((ks * 4 + lg) ^ x) << 3;
        kf[nt][ks] = *reinterpret_cast<const s16x8*>(&kt[row * 64 + c]);
      }
    }
    f32x4 sv[4];
    __builtin_amdgcn_s_setprio(1);
#pragma unroll
    for (int nt = 0; nt < 4; ++nt) {
      f32x4 z = {};
      z = __builtin_amdgcn_mfma_f32_16x16x32_bf16(kf[nt][0], qf0, z, 0, 0, 0);
      z = __builtin_amdgcn_mfma_f32_16x16x32_bf16(kf[nt][1], qf1, z, 0, 0, 0);
      sv[nt] = z;
    }
    __builtin_amdgcn_s_setprio(0);
    s16x8 vf[4][2];
#pragma unroll
    for (int nt = 0; nt < 4; ++nt) {
      const int row = nt * 16 + lr;
      const int x = row & 7;
#pragma unroll
      for (int ks = 0; ks < 2; ++ks) {
        const int c = ((ks * 4 + lg) ^ x) << 3;
        vf[nt][ks] = *reinterpret_cast<const s16x8*>(&vt[row * 64 + c]);
      }
    }
    float pm;
    {
      f32x4 m4 = sv[0];
      m4 = {fmaxf(m4[0], sv[1][0]), fmaxf(m4[1], sv[1][1]), fmaxf(m4[2], sv[1][2]), fmaxf(m4[3], sv[1][3])};
      m4 = {fmaxf(m4[0], sv[2][0]), fmaxf(m4[1], sv[2][1]), fmaxf(m4[2], sv[2][2]), fmaxf(m4[3], sv[2][3])};
      m4 = {fmaxf(m4[0], sv[3][0]), fmaxf(m4[1], sv[3][1]), fmaxf(m4[2], sv[3][2]), fmaxf(m4[3], sv[3][3])};
      pm = fmaxf(fmaxf(m4[0], m4[1]), fmaxf(m4[2], m4[3]));
    }
    pm = fmaxf(pm, __shfl_xor(pm, 16));
    pm = fmaxf(pm, __shfl_xor(pm, 32));
    if (!__all(pm <= mrow + 5.0f)) {
      const float mn = fmaxf(mrow, pm);
      const float scl = exp2f((mrow - mn) * LOG2E);
      ssum *= scl;
      float sc[4];
#pragma unroll
      for (int r = 0; r < 4; ++r) sc[r] = __shfl(scl, (lg << 2) | r);
#pragma unroll
      for (int nt = 0; nt < 4; ++nt)
#pragma unroll
        for (int r = 0; r < 4; ++r) ctx[nt][r] *= sc[r];
      mrow = mn;
    }
    const float ml2e = mrow * LOG2E;
    float ps = 0.f;
    uint32_t pk[4][2];
#pragma unroll
    for (int nt = 0; nt < 4; ++nt) {
      const float p0 = exp2f(sv[nt][0] * LOG2E - ml2e);
      const float p1 = exp2f(sv[nt][1] * LOG2E - ml2e);
      const float p2 = exp2f(sv[nt][2] * LOG2E - ml2e);
      const float p3 = exp2f(sv[nt][3] * LOG2E - ml2e);
      ps += (p0 + p1) + (p2 + p3);
      asm("v_cvt_pk_bf16_f32 %0, %1, %2" : "=v"(pk[nt][0]) : "v"(p0), "v"(p1));
      asm("v_cvt_pk_bf16_f32 %0, %1, %2" : "=v"(pk[nt][1]) : "v"(p2), "v"(p3));
    }
    ssum += ps;
#pragma unroll
    for (int nt = 0; nt < 4; ++nt) {
      uint2 d; d.x = pk[nt][0]; d.y = pk[nt][1];
      *reinterpret_cast<uint2*>(&pw[lr * 72 + nt * 16 + lg * 4]) = d;
    }
    asm volatile("s_waitcnt lgkmcnt(0)" ::: "memory");
    __builtin_amdgcn_sched_barrier(0);
    const s16x8 pa0 = *reinterpret_cast<const s16x8*>(&pw[lr * 72 + lg * 8]);
    const s16x8 pa1 = *reinterpret_cast<const s16x8*>(&pw[lr * 72 + 32 + lg * 8]);
    __builtin_amdgcn_s_setprio(1);
#pragma unroll
    for (int nt = 0; nt < 4; ++nt) {
      ctx[nt] = __builtin_amdgcn_mfma_f32_16x16x32_bf16(pa0, vf[nt][0], ctx[nt], 0, 0, 0);
      ctx[nt] = __builtin_amdgcn_mfma_f32_16x16x32_bf16(pa1, vf[nt][1], ctx[nt], 0, 0, 0);
    }
    __builtin_amdgcn_s_setprio(0);
  };

  int p = 0;
  stage(0, su0);
  for (int ut = su0; ut < su1; ++ut) {
    __builtin_amdgcn_s_barrier();
    if (ut + 1 < su1) {
      stage(p ^ 1, ut + 1);
      asm volatile("s_waitcnt vmcnt(2)" ::: "memory");
    } else {
      asm volatile("s_waitcnt vmcnt(0)" ::: "memory");
    }
    __builtin_amdgcn_s_barrier();
    if (ut >= dc && ut <= 8 + dc) compute(p);
    p ^= 1;
  }

  float s = ssum;
  s += __shfl_xor(s, 16);
  s += __shfl_xor(s, 32);
  const float invq = 1.f / s;
  float ic[4];
#pragma unroll
  for (int r = 0; r < 4; ++r) ic[r] = __shfl(invq, (lg << 2) | r);

  const int tok = cw * 64 + (w & 3) * 16 + lg * 4;
#pragma unroll
  for (int nt = 0; nt < 4; ++nt) {
    const int col = h * 64 + nt * 16 + lr;
#pragma unroll
    for (int r = 0; r < 4; ++r)
      ctx_ws[(size_t)(b * Sc + tok + r) * Ec + col] = f2b(ctx[nt][r] * ic[r]);
  }
}

extern "C" void kernel_launch(void* const* d_in, const int* in_sizes, int n_in,
                              void* d_out, int out_size, void* d_ws, size_t ws_size,
                              hipStream_t stream) {
  const float* hs = (const float*)d_in[0];
  const float* Wq = (const float*)d_in[1];
  const float* bq = (const float*)d_in[2];
  const float* Wk = (const float*)d_in[3];
  const float* bk = (const float*)d_in[4];
  const float* Wv = (const float*)d_in[5];
  const float* bv = (const float*)d_in[6];
  const float* Wo = (const float*)d_in[7];
  const float* bo = (const float*)d_in[8];
  float* out = (float*)d_out;

  char* ws = (char*)d_ws;
  size_t o = 0;
  u16* hsb = (u16*)(ws + o);   o += (size_t)Mrows * Ec * 2;
  u16* wqkvt = (u16*)(ws + o); o += (size_t)3 * Ec * Ec * 2;
  u16* wot = (u16*)(ws + o);   o += (size_t)Ec * Ec * 2;
  u16* q_ws = (u16*)(ws + o);  o += (size_t)Mrows * Ec * 2;      // [b,h,s,d]
  u16* k_ws = (u16*)(ws + o);  o += (size_t)Mrows * Ec * 2;      // [b,h,s,d]
  u16* vt_ws = (u16*)(ws + o); o += (size_t)Mrows * Ec * 2;      // [b,h,d,s]
  u16* ctx_ws = (u16*)(ws + o); o += (size_t)Mrows * Ec * 2;     // [b*s, e]

  const int nhs = Mrows * Ec;
  k_prep<<<6144 + 4 * 576, 256, 0, stream>>>(hs, hsb, nhs, Wq, Wk, Wv, Wo, wqkvt, wot);

  k_gemm_qkv<<<2304, 256, 0, stream>>>(hsb, wqkvt, bq, bk, bv, q_ws, k_ws, vt_ws);

  k_attn<<<768, 512, 0, stream>>>(q_ws, k_ws, vt_ws, ctx_ws);

  k_gemm_out<<<768, 256, 0, stream>>>(ctx_ws, wot, bo, out);
}

// Round 16
// 108.778 us; speedup vs baseline: 1.2126x; 1.1665x over previous
//
#include <hip/hip_runtime.h>
#include <stdint.h>

typedef unsigned short u16;
typedef short s16x8 __attribute__((ext_vector_type(8)));
typedef float f32x4 __attribute__((ext_vector_type(4)));

#define LOG2E 1.44269504088896340736f

constexpr int Bc = 2, Sc = 4096, Ec = 768, Hc = 12;
constexpr int Mrows = Bc * Sc; // 8192

__device__ __forceinline__ u16 f2b(float x) {
  union { float f; uint32_t u; } v; v.f = x;
  return (u16)((v.u + 0x7FFFu + ((v.u >> 16) & 1u)) >> 16);
}

__device__ __forceinline__ void gld16(const u16* g, u16* l) {
  __builtin_amdgcn_global_load_lds(
      (const __attribute__((address_space(1))) void*)g,
      (__attribute__((address_space(3))) void*)l,
      16, 0, 0);
}

// ---------------- fused prep: hs cvt + 4 weight transpose-cvts ----------------
__global__ __launch_bounds__(256) void k_prep(
    const float* __restrict__ hs, u16* __restrict__ hsb, int nhs,
    const float* __restrict__ Wq, const float* __restrict__ Wk,
    const float* __restrict__ Wv, const float* __restrict__ Wo,
    u16* __restrict__ wqkvt, u16* __restrict__ wot) {
  __shared__ float tbuf[32][33];
  const int bid = blockIdx.x;
  const int tid = threadIdx.x;
  if (bid < 6144) { // cvt: 6144 * 1024 elems = nhs
    const int i = (bid * 256 + tid) * 4;
    if (i >= nhs) return;
    const float4 v = *reinterpret_cast<const float4*>(hs + i);
    ushort4 o;
    o.x = f2b(v.x); o.y = f2b(v.y); o.z = f2b(v.z); o.w = f2b(v.w);
    *reinterpret_cast<ushort4*>(hsb + i) = o;
  } else { // transpose-cvt: 4 weights x 576 tiles of 32x32
    const int t = bid - 6144;
    const int widx = t / 576;
    const int inner = t - widx * 576;
    const float* in = (widx == 0) ? Wq : (widx == 1) ? Wk : (widx == 2) ? Wv : Wo;
    u16* out = (widx < 3) ? (wqkvt + (size_t)widx * Ec * Ec) : wot;
    const int c0 = (inner % 24) * 32, r0 = (inner / 24) * 32;
    const int tx = tid & 31, ty = tid >> 5;
#pragma unroll
    for (int i = 0; i < 32; i += 8)
      tbuf[ty + i][tx] = in[(size_t)(r0 + ty + i) * Ec + c0 + tx];
    __syncthreads();
#pragma unroll
    for (int i = 0; i < 32; i += 8)
      out[(size_t)(c0 + ty + i) * Ec + r0 + tx] = f2b(tbuf[tx][ty + i]);
  }
}

// ======================= QKV GEMM — r12 discipline, BK=64 =======================
// 64x128 tile (4 waves of 64x32), BK=64, 2 LDS buffers (48 KB). Same loop
// discipline as r12 (vmcnt(0) -> barrier -> stage(k+1) -> reads -> MFMA) but
// 12 iterations instead of 24: each drain+barrier amortized over 2x MFMA work.
// Occupancy measured only ~2.25 blocks/CU at 24 KB, so 48 KB costs nothing.
// Swizzle: u = g ^ (row&7) (r8-verified, conflicts 0).
__global__ __launch_bounds__(256) void k_gemm_qkv(
    const u16* __restrict__ A, const u16* __restrict__ Bt,
    const float* __restrict__ bq, const float* __restrict__ bk, const float* __restrict__ bv,
    u16* __restrict__ q_ws, u16* __restrict__ k_ws, u16* __restrict__ vt_ws) {
  __shared__ __align__(16) u16 As[2][64 * 64];
  __shared__ __align__(16) u16 Bs[2][128 * 64];
  const int bid = blockIdx.x;
  const int xcd = bid & 7, ii = bid >> 3;          // ii in 0..287
  const int m0 = (xcd * 16 + (ii & 15)) * 64;      // 128 M-tiles, 16 per XCD
  const int n0 = (ii >> 4) * 128;                  // 18 N-tiles
  const int which = n0 / Ec;                       // 0=q 1=k 2=v (uniform)
  const bool isV = (which == 2);
  const int tid = threadIdx.x;
  const int lane = tid & 63, w = tid >> 6;         // wave owns n-cols [w*32, w*32+32)
  const int lr = lane & 15, lg = lane >> 4;

  f32x4 acc[4][2] = {};

  const int srow = tid >> 3; // 0..31 (wave w covers rows w*8..w*8+7 per pass)
  const int su = tid & 7;

  auto stage = [&](int p, int ki) {
    const int k0 = ki * 64;
#pragma unroll
    for (int r2 = 0; r2 < 2; ++r2) {
      const int row = r2 * 32 + srow;
      const int sc = ((su ^ (row & 7)) << 3);
      gld16(A + (size_t)(m0 + row) * Ec + k0 + sc, &As[p][(r2 * 32 + w * 8) * 64]);
    }
#pragma unroll
    for (int r2 = 0; r2 < 4; ++r2) {
      const int row = r2 * 32 + srow;
      const int sc = ((su ^ (row & 7)) << 3);
      gld16(Bt + (size_t)(n0 + row) * Ec + k0 + sc, &Bs[p][(r2 * 32 + w * 8) * 64]);
    }
  };

  constexpr int NK = Ec / 64; // 12
  stage(0, 0);
  for (int ki = 0; ki < NK; ++ki) {
    const int p = ki & 1;
    asm volatile("s_waitcnt vmcnt(0)" ::: "memory"); // buf[p] staged (1-iter cover)
    __builtin_amdgcn_s_barrier();
    if (ki + 1 < NK) stage(p ^ 1, ki + 1);           // hides under compute below
    s16x8 af[4][2], bf[2][2];
#pragma unroll
    for (int i = 0; i < 4; ++i) {
      const int ra = i * 16 + lr;
#pragma unroll
      for (int ks = 0; ks < 2; ++ks)
        af[i][ks] = *reinterpret_cast<const s16x8*>(&As[p][ra * 64 + (((ks * 4 + lg) ^ (ra & 7)) << 3)]);
    }
#pragma unroll
    for (int i = 0; i < 2; ++i) {
      const int rb = w * 32 + i * 16 + lr;
#pragma unroll
      for (int ks = 0; ks < 2; ++ks)
        bf[i][ks] = *reinterpret_cast<const s16x8*>(&Bs[p][rb * 64 + (((ks * 4 + lg) ^ (rb & 7)) << 3)]);
    }
    __builtin_amdgcn_s_setprio(1);
    if (isV) {
#pragma unroll
      for (int ks = 0; ks < 2; ++ks)
#pragma unroll
        for (int mf = 0; mf < 4; ++mf)
#pragma unroll
          for (int nf = 0; nf < 2; ++nf)
            acc[mf][nf] = __builtin_amdgcn_mfma_f32_16x16x32_bf16(af[mf][ks], bf[nf][ks], acc[mf][nf], 0, 0, 0);
    } else {
#pragma unroll
      for (int ks = 0; ks < 2; ++ks)
#pragma unroll
        for (int nf = 0; nf < 2; ++nf)
#pragma unroll
          for (int mf = 0; mf < 4; ++mf)
            acc[mf][nf] = __builtin_amdgcn_mfma_f32_16x16x32_bf16(bf[nf][ks], af[mf][ks], acc[mf][nf], 0, 0, 0);
    }
    __builtin_amdgcn_s_setprio(0);
  }

  if (isV) {
#pragma unroll
    for (int nf = 0; nf < 2; ++nf) {
      const int nl = (n0 - 2 * Ec) + w * 32 + nf * 16 + lr;
      const int hh = nl >> 6, dd = nl & 63;
      const float bias = bv[nl];
#pragma unroll
      for (int mf = 0; mf < 4; ++mf) {
        const int mg = m0 + mf * 16 + lg * 4;
        const int bb = mg >> 12, ss = mg & (Sc - 1);
        const int bh = bb * Hc + hh;
        ushort4 pk;
        pk.x = f2b(acc[mf][nf][0] + bias);
        pk.y = f2b(acc[mf][nf][1] + bias);
        pk.z = f2b(acc[mf][nf][2] + bias);
        pk.w = f2b(acc[mf][nf][3] + bias);
        *reinterpret_cast<ushort4*>(&vt_ws[((size_t)bh * 64 + dd) * Sc + ss]) = pk;
      }
    }
  } else {
    const float* bptr = (which == 0) ? bq : bk;
    u16* dst = (which == 0) ? q_ws : k_ws;
    const float scl = (which == 0) ? 0.125f : 1.0f;
    const int nbase = n0 - which * Ec;
#pragma unroll
    for (int nf = 0; nf < 2; ++nf) {
      const int nl0 = nbase + w * 32 + nf * 16 + lg * 4;
      const int hh = nl0 >> 6, dd0 = nl0 & 63;
      const float4 b4 = *reinterpret_cast<const float4*>(bptr + nl0);
#pragma unroll
      for (int mf = 0; mf < 4; ++mf) {
        const int tok = m0 + mf * 16 + lr;
        const int bb = tok >> 12, ss = tok & (Sc - 1);
        const float v0 = (acc[mf][nf][0] + b4.x) * scl;
        const float v1 = (acc[mf][nf][1] + b4.y) * scl;
        const float v2 = (acc[mf][nf][2] + b4.z) * scl;
        const float v3 = (acc[mf][nf][3] + b4.w) * scl;
        uint32_t w0, w1;
        asm("v_cvt_pk_bf16_f32 %0, %1, %2" : "=v"(w0) : "v"(v0), "v"(v1));
        asm("v_cvt_pk_bf16_f32 %0, %1, %2" : "=v"(w1) : "v"(v2), "v"(v3));
        uint2 d; d.x = w0; d.y = w1;
        *reinterpret_cast<uint2*>(&dst[((size_t)((bb * Hc + hh) * Sc + ss)) * 64 + dd0]) = d;
      }
    }
  }
}

// ======================= output GEMM — same BK=64 structure =======================
__global__ __launch_bounds__(256) void k_gemm_out(
    const u16* __restrict__ A, const u16* __restrict__ Bt,
    const float* __restrict__ bo, float* __restrict__ out) {
  __shared__ __align__(16) u16 As[2][64 * 64];
  __shared__ __align__(16) u16 Bs[2][128 * 64];
  const int bid = blockIdx.x;
  const int xcd = bid & 7, ii = bid >> 3;          // ii in 0..95
  const int m0 = (xcd * 16 + (ii & 15)) * 64;
  const int n0 = (ii >> 4) * 128;                  // 6 N-tiles
  const int tid = threadIdx.x;
  const int lane = tid & 63, w = tid >> 6;
  const int lr = lane & 15, lg = lane >> 4;

  f32x4 acc[4][2] = {};
  const int srow = tid >> 3;
  const int su = tid & 7;

  auto stage = [&](int p, int ki) {
    const int k0 = ki * 64;
#pragma unroll
    for (int r2 = 0; r2 < 2; ++r2) {
      const int row = r2 * 32 + srow;
      const int sc = ((su ^ (row & 7)) << 3);
      gld16(A + (size_t)(m0 + row) * Ec + k0 + sc, &As[p][(r2 * 32 + w * 8) * 64]);
    }
#pragma unroll
    for (int r2 = 0; r2 < 4; ++r2) {
      const int row = r2 * 32 + srow;
      const int sc = ((su ^ (row & 7)) << 3);
      gld16(Bt + (size_t)(n0 + row) * Ec + k0 + sc, &Bs[p][(r2 * 32 + w * 8) * 64]);
    }
  };

  constexpr int NK = Ec / 64; // 12
  stage(0, 0);
  for (int ki = 0; ki < NK; ++ki) {
    const int p = ki & 1;
    asm volatile("s_waitcnt vmcnt(0)" ::: "memory");
    __builtin_amdgcn_s_barrier();
    if (ki + 1 < NK) stage(p ^ 1, ki + 1);
    s16x8 af[4][2], bf[2][2];
#pragma unroll
    for (int i = 0; i < 4; ++i) {
      const int ra = i * 16 + lr;
#pragma unroll
      for (int ks = 0; ks < 2; ++ks)
        af[i][ks] = *reinterpret_cast<const s16x8*>(&As[p][ra * 64 + (((ks * 4 + lg) ^ (ra & 7)) << 3)]);
    }
#pragma unroll
    for (int i = 0; i < 2; ++i) {
      const int rb = w * 32 + i * 16 + lr;
#pragma unroll
      for (int ks = 0; ks < 2; ++ks)
        bf[i][ks] = *reinterpret_cast<const s16x8*>(&Bs[p][rb * 64 + (((ks * 4 + lg) ^ (rb & 7)) << 3)]);
    }
    __builtin_amdgcn_s_setprio(1);
#pragma unroll
    for (int ks = 0; ks < 2; ++ks)
#pragma unroll
      for (int nf = 0; nf < 2; ++nf)
#pragma unroll
        for (int mf = 0; mf < 4; ++mf)
          acc[mf][nf] = __builtin_amdgcn_mfma_f32_16x16x32_bf16(bf[nf][ks], af[mf][ks], acc[mf][nf], 0, 0, 0);
    __builtin_amdgcn_s_setprio(0);
  }

#pragma unroll
  for (int nf = 0; nf < 2; ++nf) {
    const int f0 = n0 + w * 32 + nf * 16 + lg * 4;
    const float4 b4 = *reinterpret_cast<const float4*>(bo + f0);
#pragma unroll
    for (int mf = 0; mf < 4; ++mf) {
      const int tok = m0 + mf * 16 + lr;
      float4 o;
      o.x = acc[mf][nf][0] + b4.x;
      o.y = acc[mf][nf][1] + b4.y;
      o.z = acc[mf][nf][2] + b4.z;
      o.w = acc[mf][nf][3] + b4.w;
      *reinterpret_cast<float4*>(&out[(size_t)tok * Ec + f0]) = o;
    }
  }
}

// ---------------- local attention: 2 chunks per block (round-9, verified) ----------------
__global__ __launch_bounds__(512) void k_attn(
    const u16* __restrict__ q_ws, const u16* __restrict__ k_ws,
    const u16* __restrict__ vt_ws, u16* __restrict__ ctx_ws) {
  __shared__ __align__(16) u16 Kb[2][64 * 64];
  __shared__ __align__(16) u16 Vb[2][64 * 64];
  __shared__ __align__(16) u16 P[8][16 * 72];
  const int lin = blockIdx.x;
  const int work = (lin & 7) * 96 + (lin >> 3);
  const int bh = work >> 5;
  const int cp = work & 31;
  const int c0 = cp * 2;
  const int tid = threadIdx.x;
  const int lane = tid & 63, w = tid >> 6;
  const int dc = w >> 2;
  const int cw = c0 + dc;
  const int b = bh / Hc, h = bh - b * Hc;
  const int lr = lane & 15, lg = lane >> 4;

  const u16* qb = q_ws + (size_t)bh * Sc * 64;
  const u16* kb = k_ws + (size_t)bh * Sc * 64;
  const u16* vb = vt_ws + (size_t)bh * 64 * Sc;

  const int qrow = cw * 64 + (w & 3) * 16 + lr;
  const s16x8 qf0 = *reinterpret_cast<const s16x8*>(&qb[(size_t)qrow * 64 + lg * 8]);
  const s16x8 qf1 = *reinterpret_cast<const s16x8*>(&qb[(size_t)qrow * 64 + 32 + lg * 8]);

  float mrow = -3e38f;
  float ssum = 0.f;
  f32x4 ctx[4] = {};

  const int su0 = (c0 < 4) ? 4 - c0 : 0;
  const int su1 = (68 - c0 < 10) ? 68 - c0 : 10;
  u16* pw = &P[w][0];

  const int srow = tid >> 3;
  const int su8 = tid & 7;

  auto stage = [&](int p, int ut) {
    const int key0 = (c0 - 4 + ut) * 64;
    const int sw = ((su8 ^ (srow & 7)) << 3);
    gld16(kb + (size_t)(key0 + srow) * 64 + sw, &Kb[p][w * 512]);
    gld16(vb + (size_t)srow * Sc + key0 + sw, &Vb[p][w * 512]);
  };

  auto compute = [&](int p) {
    const u16* kt = &Kb[p][0];
    const u16* vt = &Vb[p][0];
    s16x8 kf[4][2];
#pragma unroll
    for (int nt = 0; nt < 4; ++nt) {
      const int row = nt * 16 + lr;
      const int x = row & 7;
#pragma unroll
      for (int ks = 0; ks < 2; ++ks) {
        const int c = ((ks * 4 + lg) ^ x) << 3;
        kf[nt][ks] = *reinterpret_cast<const s16x8*>(&kt[row * 64 + c]);
      }
    }
    f32x4 sv[4];
    __builtin_amdgcn_s_setprio(1);
#pragma unroll
    for (int nt = 0; nt < 4; ++nt) {
      f32x4 z = {};
      z = __builtin_amdgcn_mfma_f32_16x16x32_bf16(kf[nt][0], qf0, z, 0, 0, 0);
      z = __builtin_amdgcn_mfma_f32_16x16x32_bf16(kf[nt][1], qf1, z, 0, 0, 0);
      sv[nt] = z;
    }
    __builtin_amdgcn_s_setprio(0);
    s16x8 vf[4][2];
#pragma unroll
    for (int nt = 0; nt < 4; ++nt) {
      const int row = nt * 16 + lr;
      const int x = row & 7;
#pragma unroll
      for (int ks = 0; ks < 2; ++ks) {
        const int c = ((ks * 4 + lg) ^ x) << 3;
        vf[nt][ks] = *reinterpret_cast<const s16x8*>(&vt[row * 64 + c]);
      }
    }
    float pm;
    {
      f32x4 m4 = sv[0];
      m4 = {fmaxf(m4[0], sv[1][0]), fmaxf(m4[1], sv[1][1]), fmaxf(m4[2], sv[1][2]), fmaxf(m4[3], sv[1][3])};
      m4 = {fmaxf(m4[0], sv[2][0]), fmaxf(m4[1], sv[2][1]), fmaxf(m4[2], sv[2][2]), fmaxf(m4[3], sv[2][3])};
      m4 = {fmaxf(m4[0], sv[3][0]), fmaxf(m4[1], sv[3][1]), fmaxf(m4[2], sv[3][2]), fmaxf(m4[3], sv[3][3])};
      pm = fmaxf(fmaxf(m4[0], m4[1]), fmaxf(m4[2], m4[3]));
    }
    pm = fmaxf(pm, __shfl_xor(pm, 16));
    pm = fmaxf(pm, __shfl_xor(pm, 32));
    if (!__all(pm <= mrow + 5.0f)) {
      const float mn = fmaxf(mrow, pm);
      const float scl = exp2f((mrow - mn) * LOG2E);
      ssum *= scl;
      float sc[4];
#pragma unroll
      for (int r = 0; r < 4; ++r) sc[r] = __shfl(scl, (lg << 2) | r);
#pragma unroll
      for (int nt = 0; nt < 4; ++nt)
#pragma unroll
        for (int r = 0; r < 4; ++r) ctx[nt][r] *= sc[r];
      mrow = mn;
    }
    const float ml2e = mrow * LOG2E;
    float ps = 0.f;
    uint32_t pk[4][2];
#pragma unroll
    for (int nt = 0; nt < 4; ++nt) {
      const float p0 = exp2f(sv[nt][0] * LOG2E - ml2e);
      const float p1 = exp2f(sv[nt][1] * LOG2E - ml2e);
      const float p2 = exp2f(sv[nt][2] * LOG2E - ml2e);
      const float p3 = exp2f(sv[nt][3] * LOG2E - ml2e);
      ps += (p0 + p1) + (p2 + p3);
      asm("v_cvt_pk_bf16_f32 %0, %1, %2" : "=v"(pk[nt][0]) : "v"(p0), "v"(p1));
      asm("v_cvt_pk_bf16_f32 %0, %1, %2" : "=v"(pk[nt][1]) : "v"(p2), "v"(p3));
    }
    ssum += ps;
#pragma unroll
    for (int nt = 0; nt < 4; ++nt) {
      uint2 d; d.x = pk[nt][0]; d.y = pk[nt][1];
      *reinterpret_cast<uint2*>(&pw[lr * 72 + nt * 16 + lg * 4]) = d;
    }
    asm volatile("s_waitcnt lgkmcnt(0)" ::: "memory");
    __builtin_amdgcn_sched_barrier(0);
    const s16x8 pa0 = *reinterpret_cast<const s16x8*>(&pw[lr * 72 + lg * 8]);
    const s16x8 pa1 = *reinterpret_cast<const s16x8*>(&pw[lr * 72 + 32 + lg * 8]);
    __builtin_amdgcn_s_setprio(1);
#pragma unroll
    for (int nt = 0; nt < 4; ++nt) {
      ctx[nt] = __builtin_amdgcn_mfma_f32_16x16x32_bf16(pa0, vf[nt][0], ctx[nt], 0, 0, 0);
      ctx[nt] = __builtin_amdgcn_mfma_f32_16x16x32_bf16(pa1, vf[nt][1], ctx[nt], 0, 0, 0);
    }
    __builtin_amdgcn_s_setprio(0);
  };

  int p = 0;
  stage(0, su0);
  for (int ut = su0; ut < su1; ++ut) {
    __builtin_amdgcn_s_barrier();
    if (ut + 1 < su1) {
      stage(p ^ 1, ut + 1);
      asm volatile("s_waitcnt vmcnt(2)" ::: "memory");
    } else {
      asm volatile("s_waitcnt vmcnt(0)" ::: "memory");
    }
    __builtin_amdgcn_s_barrier();
    if (ut >= dc && ut <= 8 + dc) compute(p);
    p ^= 1;
  }

  float s = ssum;
  s += __shfl_xor(s, 16);
  s += __shfl_xor(s, 32);
  const float invq = 1.f / s;
  float ic[4];
#pragma unroll
  for (int r = 0; r < 4; ++r) ic[r] = __shfl(invq, (lg << 2) | r);

  const int tok = cw * 64 + (w & 3) * 16 + lg * 4;
#pragma unroll
  for (int nt = 0; nt < 4; ++nt) {
    const int col = h * 64 + nt * 16 + lr;
#pragma unroll
    for (int r = 0; r < 4; ++r)
      ctx_ws[(size_t)(b * Sc + tok + r) * Ec + col] = f2b(ctx[nt][r] * ic[r]);
  }
}

extern "C" void kernel_launch(void* const* d_in, const int* in_sizes, int n_in,
                              void* d_out, int out_size, void* d_ws, size_t ws_size,
                              hipStream_t stream) {
  const float* hs = (const float*)d_in[0];
  const float* Wq = (const float*)d_in[1];
  const float* bq = (const float*)d_in[2];
  const float* Wk = (const float*)d_in[3];
  const float* bk = (const float*)d_in[4];
  const float* Wv = (const float*)d_in[5];
  const float* bv = (const float*)d_in[6];
  const float* Wo = (const float*)d_in[7];
  const float* bo = (const float*)d_in[8];
  float* out = (float*)d_out;

  char* ws = (char*)d_ws;
  size_t o = 0;
  u16* hsb = (u16*)(ws + o);   o += (size_t)Mrows * Ec * 2;
  u16* wqkvt = (u16*)(ws + o); o += (size_t)3 * Ec * Ec * 2;
  u16* wot = (u16*)(ws + o);   o += (size_t)Ec * Ec * 2;
  u16* q_ws = (u16*)(ws + o);  o += (size_t)Mrows * Ec * 2;      // [b,h,s,d]
  u16* k_ws = (u16*)(ws + o);  o += (size_t)Mrows * Ec * 2;      // [b,h,s,d]
  u16* vt_ws = (u16*)(ws + o); o += (size_t)Mrows * Ec * 2;      // [b,h,d,s]
  u16* ctx_ws = (u16*)(ws + o); o += (size_t)Mrows * Ec * 2;     // [b*s, e]

  const int nhs = Mrows * Ec;
  k_prep<<<6144 + 4 * 576, 256, 0, stream>>>(hs, hsb, nhs, Wq, Wk, Wv, Wo, wqkvt, wot);

  k_gemm_qkv<<<2304, 256, 0, stream>>>(hsb, wqkvt, bq, bk, bv, q_ws, k_ws, vt_ws);

  k_attn<<<768, 512, 0, stream>>>(q_ws, k_ws, vt_ws, ctx_ws);

  k_gemm_out<<<768, 256, 0, stream>>>(ctx_ws, wot, bo, out);
}